// Round 4
// baseline (64.004 us; speedup 1.0000x reference)
//
#include <hip/hip_runtime.h>

// spikes = (floor(v0 + cumsum(relu(x)*DT)) - floor(prev)) / DT, f64 scan.
// (f32 scan flips floors vs the f64 np reference — R0/R1 failures; f64
// reassociation across segments is ~1e-16 and validated safe in R3.)
//
// R3 (single kernel, 16 in-block segments) = 57.4us, 74% of achievable BW,
// dword-granular streams, geometry locked to VEC=1. This version decouples
// into two kernels via a f64 segsum workspace so both phases run VEC=4
// float4 streams with free grid shape:
//   K1: ws[g][c] = in-order f64 sum of rates over segment g of chain c.
//   K3: prefix = in-order sum ws[0..g-1][c]; re-read input (LLC-resident),
//       emit. NSEG=32, 512 blocks x 256 thr per kernel, 8 waves/CU.

#pragma clang fp contract(off)   // np rounds rate before accumulating: no FMA

constexpr int B = 16;
constexpr int T = 2048;
constexpr int D = 1024;
constexpr int NCHAIN = B * D;    // 16384
constexpr int VEC = 4;           // chains per thread (float4 streams)
constexpr int THREADS = 256;
constexpr int U = 8;             // float4 t-steps per load chunk

__global__ __launch_bounds__(THREADS, 4)
void seg_sum_kernel(const float* __restrict__ in, double* __restrict__ ws,
                    int tseg) {
  const int tid = blockIdx.x * THREADS + threadIdx.x;
  const int g = blockIdx.y;
  const int c = tid * VEC;                 // first chain of this thread
  const int b = c >> 10;                   // D = 1024; VEC | D so no b-cross
  const int d = c & (D - 1);
  const float4* __restrict__ ip =
      (const float4*)(in + (size_t)b * T * D + (size_t)g * tseg * D + d);
  const int strd = D / 4;

  double s0 = 0, s1 = 0, s2 = 0, s3 = 0;
  for (int t = 0; t < tseg; t += U) {
    float4 buf[U];
#pragma unroll
    for (int u = 0; u < U; ++u) buf[u] = ip[(size_t)(t + u) * strd];
#pragma unroll
    for (int u = 0; u < U; ++u) {
      s0 += fmax((double)buf[u].x, 0.0) * 0.001;
      s1 += fmax((double)buf[u].y, 0.0) * 0.001;
      s2 += fmax((double)buf[u].z, 0.0) * 0.001;
      s3 += fmax((double)buf[u].w, 0.0) * 0.001;
    }
  }
  double* w = ws + (size_t)g * NCHAIN + c;
  w[0] = s0; w[1] = s1; w[2] = s2; w[3] = s3;
}

__global__ __launch_bounds__(THREADS, 4)
void emit_kernel(const float* __restrict__ in, const float* __restrict__ state,
                 const double* __restrict__ ws, float* __restrict__ out,
                 int tseg) {
  const int tid = blockIdx.x * THREADS + threadIdx.x;
  const int g = blockIdx.y;
  const int c = tid * VEC;
  const int b = c >> 10;
  const int d = c & (D - 1);
  const size_t base = (size_t)b * T * D + (size_t)g * tseg * D + d;
  const float4* __restrict__ ip = (const float4*)(in + base);
  float4* __restrict__ op = (float4*)(out + base);
  const int strd = D / 4;

  // In-order prefix over preceding segments (deterministic, ascending w).
  double s0 = 0, s1 = 0, s2 = 0, s3 = 0;
  for (int w = 0; w < g; ++w) {
    const double* p = ws + (size_t)w * NCHAIN + c;
    s0 += p[0]; s1 += p[1]; s2 += p[2]; s3 += p[3];
  }
  const float4 v0f = *(const float4*)(state + c);
  const double v00 = (double)v0f.x, v01 = (double)v0f.y;
  const double v02 = (double)v0f.z, v03 = (double)v0f.w;
  double p0 = floor(v00 + s0), p1 = floor(v01 + s1);
  double p2 = floor(v02 + s2), p3 = floor(v03 + s3);

  for (int t = 0; t < tseg; t += U) {
    float4 buf[U];
#pragma unroll
    for (int u = 0; u < U; ++u) buf[u] = ip[(size_t)(t + u) * strd];
#pragma unroll
    for (int u = 0; u < U; ++u) {
      s0 += fmax((double)buf[u].x, 0.0) * 0.001;
      s1 += fmax((double)buf[u].y, 0.0) * 0.001;
      s2 += fmax((double)buf[u].z, 0.0) * 0.001;
      s3 += fmax((double)buf[u].w, 0.0) * 0.001;
      const double f0 = floor(v00 + s0), f1 = floor(v01 + s1);
      const double f2 = floor(v02 + s2), f3 = floor(v03 + s3);
      float4 o;
      o.x = (float)((f0 - p0) * 1000.0);
      o.y = (float)((f1 - p1) * 1000.0);
      o.z = (float)((f2 - p2) * 1000.0);
      o.w = (float)((f3 - p3) * 1000.0);
      op[(size_t)(t + u) * strd] = o;
      p0 = f0; p1 = f1; p2 = f2; p3 = f3;
    }
  }
}

extern "C" void kernel_launch(void* const* d_in, const int* in_sizes, int n_in,
                              void* d_out, int out_size, void* d_ws, size_t ws_size,
                              hipStream_t stream) {
  const float* in = (const float*)d_in[0];     // [B, T, D] f32
  const float* st = (const float*)d_in[1];     // [B, D]    f32
  float* out = (float*)d_out;                  // [B, T, D] f32
  double* ws = (double*)d_ws;                  // [nseg][NCHAIN] f64 segsums

  int nseg = 32;                               // 4 MB ws; halve if ws smaller
  while (nseg > 1 && (size_t)nseg * NCHAIN * sizeof(double) > ws_size) nseg >>= 1;
  const int tseg = T / nseg;                   // 64 at nseg=32 (multiple of U)

  dim3 grid(NCHAIN / (VEC * THREADS), nseg);   // (16, nseg) blocks
  if (nseg > 1)
    seg_sum_kernel<<<grid, THREADS, 0, stream>>>(in, ws, tseg);
  emit_kernel<<<grid, THREADS, 0, stream>>>(in, st, ws, out, tseg);
}